// Round 8
// baseline (17718.442 us; speedup 1.0000x reference)
//
#include <hip/hip_runtime.h>
#include <hip/hip_bf16.h>
#include <math.h>

#define DEVFN __device__ __forceinline__

constexpr int B_ = 16, N_ = 512, K_ = 30, H_ = 128;
constexpr int NH_ = 4, V_ = 20;
constexpr int BN_ = B_ * N_;
constexpr float NEG_INF_ = -3.4028235e38f;

DEVFN double block_sum128d(double v, double* sbuf) {
  int t = threadIdx.x;
  sbuf[t] = v; __syncthreads();
  #pragma unroll
  for (int s = 64; s > 0; s >>= 1) {
    if (t < s) sbuf[t] += sbuf[t + s];
    __syncthreads();
  }
  double r = sbuf[0];
  __syncthreads();
  return r;
}

// ---------------- top-K neighbors: distances BIT-EXACT to plain numpy float32 ----------------
// np: D = mask2d * sqrt(sum(dX*dX, -1) + 1e-6); square/sum/sqrt each individually rounded,
// sequential sum, NO FMA. __f*_rn intrinsics forbid contraction.
// TIE-BREAK: higher index wins among bitwise-equal distances (matches observed np ref
// behavior at exact ties; within-K order is permutation-invariant downstream).
__global__ __launch_bounds__(256) void topk_kernel(const float* __restrict__ X,
    const float* __restrict__ mask, int* __restrict__ E_idx, float* __restrict__ Dnb) {
  __shared__ float xs[N_ * 3];
  __shared__ float ds[N_];
  __shared__ float fred[256];
  __shared__ unsigned long long kred[256];
  int b = blockIdx.x / N_, i = blockIdx.x % N_;
  int t = threadIdx.x;
  for (int j = t; j < N_; j += 256) {
    const float* p = X + ((size_t)(b * N_ + j) * 4 + 1) * 3;  // CA atom
    xs[j * 3 + 0] = p[0]; xs[j * 3 + 1] = p[1]; xs[j * 3 + 2] = p[2];
  }
  __syncthreads();
  float xi0 = xs[i * 3], xi1 = xs[i * 3 + 1], xi2 = xs[i * 3 + 2];
  float mi = mask[b * N_ + i];
  float lmax = -3.4e38f;
  for (int j = t; j < N_; j += 256) {
    float dx = __fsub_rn(xi0, xs[j * 3]);
    float dy = __fsub_rn(xi1, xs[j * 3 + 1]);
    float dz = __fsub_rn(xi2, xs[j * 3 + 2]);
    float m2 = __fmul_rn(mi, mask[b * N_ + j]);
    float s = __fadd_rn(__fadd_rn(__fadd_rn(__fmul_rn(dx, dx), __fmul_rn(dy, dy)),
                                  __fmul_rn(dz, dz)), 1e-6f);
    float D = __fmul_rn(m2, __fsqrt_rn(s));
    ds[j] = D;
    lmax = fmaxf(lmax, D);
  }
  fred[t] = lmax; __syncthreads();
  for (int s = 128; s > 0; s >>= 1) { if (t < s) fred[t] = fmaxf(fred[t], fred[t + s]); __syncthreads(); }
  float Dmax = fred[0]; __syncthreads();
  for (int j = t; j < N_; j += 256) {
    float m2 = __fmul_rn(mi, mask[b * N_ + j]);
    ds[j] = __fadd_rn(ds[j], __fmul_rn(__fsub_rn(1.f, m2), Dmax));
  }
  __syncthreads();
  // extract K smallest; equal distances -> HIGHER index first
  for (int kk = 0; kk < K_; kk++) {
    unsigned long long best = ~0ull;
    for (int j = t; j < N_; j += 256) {
      unsigned long long key = (((unsigned long long)__float_as_uint(ds[j])) << 32)
                             | (unsigned)(N_ - 1 - j);
      if (key < best) best = key;
    }
    kred[t] = best; __syncthreads();
    for (int s = 128; s > 0; s >>= 1) { if (t < s && kred[t + s] < kred[t]) kred[t] = kred[t + s]; __syncthreads(); }
    if (t == 0) {
      unsigned long long k0 = kred[0];
      int j = N_ - 1 - (int)(k0 & 0xffffffffull);
      E_idx[blockIdx.x * K_ + kk] = j;
      Dnb[blockIdx.x * K_ + kk] = __uint_as_float((unsigned)(k0 >> 32));
      ds[j] = 3.4028235e38f;
    }
    __syncthreads();
  }
}

// ---------------- dihedral features (1 thread / node), double ----------------
DEVFN void load_atomd(const float* X, int b, int m, double* p) {
  const float* q = X + ((size_t)(b * N_ + m / 3) * 4 + (m % 3)) * 3;
  p[0] = (double)q[0]; p[1] = (double)q[1]; p[2] = (double)q[2];
}
DEVFN void cross3d(const double* a, const double* b, double* c) {
  c[0] = a[1] * b[2] - a[2] * b[1];
  c[1] = a[2] * b[0] - a[0] * b[2];
  c[2] = a[0] * b[1] - a[1] * b[0];
}
DEVFN void norm3d(double* v) {
  double n = sqrt(v[0] * v[0] + v[1] * v[1] + v[2] * v[2]) + 1e-7;
  v[0] /= n; v[1] /= n; v[2] /= n;
}
__global__ __launch_bounds__(256) void dihedral_kernel(const float* __restrict__ X, double* __restrict__ Vf) {
  int idx = blockIdx.x * blockDim.x + threadIdx.x;
  if (idx >= BN_) return;
  int b = idx / N_, n = idx % N_;
  double cs[3], sn[3];
  for (int s = 0; s < 3; s++) {
    int p = 3 * n + s;
    double a = 0.0;
    if (p >= 1 && p <= 3 * N_ - 3) {
      int tt = p - 1;
      double u[3][3];
      double prev[3], cur[3];
      load_atomd(X, b, tt, prev);
      for (int q = 0; q < 3; q++) {
        load_atomd(X, b, tt + q + 1, cur);
        double d0 = cur[0] - prev[0], d1 = cur[1] - prev[1], d2 = cur[2] - prev[2];
        double nr = sqrt(d0 * d0 + d1 * d1 + d2 * d2) + 1e-7;
        u[q][0] = d0 / nr; u[q][1] = d1 / nr; u[q][2] = d2 / nr;
        prev[0] = cur[0]; prev[1] = cur[1]; prev[2] = cur[2];
      }
      double n2v[3], n1v[3];
      cross3d(u[0], u[1], n2v); norm3d(n2v);
      cross3d(u[1], u[2], n1v); norm3d(n1v);
      double cd = n2v[0] * n1v[0] + n2v[1] * n1v[1] + n2v[2] * n1v[2];
      cd = fmin(fmax(cd, -1.0 + 1e-7), 1.0 - 1e-7);
      double dt = u[0][0] * n1v[0] + u[0][1] * n1v[1] + u[0][2] * n1v[2];
      double sg = (dt > 0.0) ? 1.0 : ((dt < 0.0) ? -1.0 : 0.0);
      a = sg * acos(cd);
    }
    cs[s] = cos(a); sn[s] = sin(a);
  }
  double* o = Vf + (size_t)idx * 6;
  o[0] = cs[0]; o[1] = cs[1]; o[2] = cs[2]; o[3] = sn[0]; o[4] = sn[1]; o[5] = sn[2];
}

// ---------------- node embed: hV = LN(V@Wfn+bfn) @ Wv + bv ----------------
__global__ __launch_bounds__(H_) void node_embed_kernel(const double* __restrict__ Vf,
    const float* __restrict__ Wfn, const float* __restrict__ bfn,
    const float* __restrict__ Wv, const float* __restrict__ bv, float* __restrict__ hV) {
  int node = blockIdx.x, t = threadIdx.x;
  __shared__ double v6[6];
  __shared__ double t1[H_];
  __shared__ double red[H_];
  if (t < 6) v6[t] = Vf[(size_t)node * 6 + t];
  __syncthreads();
  double acc = (double)bfn[t];
  for (int f = 0; f < 6; f++) acc += v6[f] * (double)Wfn[f * H_ + t];
  double mean = block_sum128d(acc, red) * (1.0 / H_);
  double d0 = acc - mean;
  double var = block_sum128d(d0 * d0, red) * (1.0 / H_);
  t1[t] = d0 / sqrt(var + 1e-6);
  __syncthreads();
  double o = (double)bv[t];
  for (int j = 0; j < H_; j++) o += t1[j] * (double)Wv[j * H_ + t];
  hV[(size_t)node * H_ + t] = (float)o;
}

// ---------------- edge embed: hE = LN(E@Wfe+bfe) @ We + be ----------------
__global__ __launch_bounds__(H_) void edge_embed_kernel(const int* __restrict__ E_idx,
    const float* __restrict__ Dnb, const float* __restrict__ Wfe, const float* __restrict__ bfe,
    const float* __restrict__ We, const float* __restrict__ be, float* __restrict__ hE) {
  int e = blockIdx.x, t = threadIdx.x;
  int n = (e / K_) % N_;
  __shared__ double feat[32];
  __shared__ double t1[H_];
  __shared__ double red[H_];
  if (t < 32) {
    double v;
    int j = E_idx[e];
    if (t < 16) {
      int jj = (t < 8) ? t : (t - 8);
      double freq = exp(-log(10000.0) * (2.0 * jj) / 16.0);
      double ang = (double)(j - n) * freq;
      v = (t < 8) ? cos(ang) : sin(ang);
    } else {
      int r = t - 16;
      double mu = 20.0 * (double)r / 15.0;
      double z = ((double)Dnb[e] - mu) / 1.25;
      v = exp(-z * z);
    }
    feat[t] = v;
  }
  __syncthreads();
  double acc = (double)bfe[t];
  for (int f = 0; f < 32; f++) acc += feat[f] * (double)Wfe[f * H_ + t];
  double mean = block_sum128d(acc, red) * (1.0 / H_);
  double d0 = acc - mean;
  double var = block_sum128d(d0 * d0, red) * (1.0 / H_);
  t1[t] = d0 / sqrt(var + 1e-6);
  __syncthreads();
  double o = (double)be[t];
  for (int j = 0; j < H_; j++) o += t1[j] * (double)We[j * H_ + t];
  hE[(size_t)e * H_ + t] = (float)o;
}

// ---------------- h_S = Ws[S] ----------------
__global__ __launch_bounds__(256) void hs_kernel(const int* __restrict__ S,
    const float* __restrict__ Ws, float* __restrict__ hS) {
  int idx = blockIdx.x * 256 + threadIdx.x;
  if (idx >= BN_ * H_) return;
  int node = idx / H_, h = idx % H_;
  hS[idx] = Ws[(size_t)S[node] * H_ + h];
}

// ---------------- fused graph attention + residual LN (double accumulation) ----------------
template<int XC, bool ENC>
__global__ __launch_bounds__(H_) void attn_kernel(const float* __restrict__ hV_in,
    const float* __restrict__ hE, const float* __restrict__ hS, const float* __restrict__ hVenc,
    const int* __restrict__ E_idx, const float* __restrict__ mask,
    const float* __restrict__ WQ, const float* __restrict__ WK,
    const float* __restrict__ WV, const float* __restrict__ WO,
    float* __restrict__ hV_out) {
  const int node = blockIdx.x;
  const int b = node / N_, n = node % N_;
  const int t = threadIdx.x;
  const int head = t >> 5, lane32 = t & 31;
  __shared__ float  x0[H_];
  __shared__ double q[H_];
  __shared__ float  xk[XC * H_];
  __shared__ float  vbuf[K_ * H_];
  __shared__ double sc[NH_ * K_];
  __shared__ double att[NH_ * K_];
  __shared__ double ob[H_];
  __shared__ double red[H_];

  x0[t] = hV_in[(size_t)node * H_ + t];
  __syncthreads();
  double acc = 0.0;
  for (int j = 0; j < H_; j++) acc += (double)x0[j] * (double)WQ[j * H_ + t];
  q[t] = acc;
  float mi = mask[b * N_ + n];

  for (int k = 0; k < K_; k++) {
    int e = node * K_ + k;
    int nb = E_idx[e];
    float c0 = hE[(size_t)e * H_ + t];
    if (ENC) {
      xk[t] = c0;
      xk[H_ + t] = hV_in[((size_t)(b * N_ + nb)) * H_ + t];
    } else {
      float ar = (nb < n) ? 1.f : 0.f;
      float bw = mi * ar, fw = mi * (1.f - ar);
      xk[t] = mi * c0;
      xk[H_ + t] = bw * hS[((size_t)(b * N_ + nb)) * H_ + t];
      xk[2 * H_ + t] = bw * hV_in[((size_t)(b * N_ + nb)) * H_ + t]
                     + fw * hVenc[((size_t)(b * N_ + nb)) * H_ + t];
    }
    __syncthreads();
    double kv = 0.0, vv = 0.0;
    for (int j = 0; j < XC * H_; j++) {
      double xv = (double)xk[j];
      kv += xv * (double)WK[j * H_ + t];
      vv += xv * (double)WV[j * H_ + t];
    }
    vbuf[k * H_ + t] = (float)vv;
    double prod = q[t] * kv;
    #pragma unroll
    for (int off = 16; off > 0; off >>= 1) prod += __shfl_xor(prod, off, 32);
    if (lane32 == 0) {
      double lg = prod * 0.17677669529663687;  // 1/sqrt(32)
      if (ENC) {
        float m2 = mi * mask[b * N_ + nb];
        sc[head * K_ + k] = (m2 > 0.f) ? lg : (double)NEG_INF_;
      } else {
        sc[head * K_ + k] = lg;
      }
    }
    __syncthreads();
  }
  if (t < NH_) {
    double mx = -1e300;
    for (int k = 0; k < K_; k++) mx = fmax(mx, sc[t * K_ + k]);
    double s = 0.0;
    for (int k = 0; k < K_; k++) { double ev = exp(sc[t * K_ + k] - mx); att[t * K_ + k] = ev; s += ev; }
    double inv = 1.0 / s;
    for (int k = 0; k < K_; k++) att[t * K_ + k] *= inv;
  }
  __syncthreads();
  if (ENC && t < K_) {
    int nb = E_idx[node * K_ + t];
    double m2 = (double)(mi * mask[b * N_ + nb]);
    for (int hh = 0; hh < NH_; hh++) att[hh * K_ + t] *= m2;
  }
  __syncthreads();
  double o = 0.0;
  for (int k = 0; k < K_; k++) o += att[head * K_ + k] * (double)vbuf[k * H_ + t];
  ob[t] = o; __syncthreads();
  double dh = 0.0;
  for (int j = 0; j < H_; j++) dh += ob[j] * (double)WO[j * H_ + t];
  double r = (double)x0[t] + dh;
  double mean = block_sum128d(r, red) * (1.0 / H_);
  double d0 = r - mean;
  double var = block_sum128d(d0 * d0, red) * (1.0 / H_);
  hV_out[(size_t)node * H_ + t] = (float)(d0 / sqrt(var + 1e-6));
}

// ---------------- FFN + residual LN + node mask (in-place, double accumulation) ----------------
__global__ __launch_bounds__(H_) void ffn_kernel(float* __restrict__ hV, const float* __restrict__ mask,
    const float* __restrict__ W1, const float* __restrict__ b1,
    const float* __restrict__ W2, const float* __restrict__ b2) {
  int node = blockIdx.x, t = threadIdx.x;
  __shared__ float x[H_];
  __shared__ float hid[4 * H_];
  __shared__ double red[H_];
  x[t] = hV[(size_t)node * H_ + t];
  __syncthreads();
  for (int c = 0; c < 4; c++) {
    int j = c * H_ + t;
    double a = (double)b1[j];
    for (int h = 0; h < H_; h++) a += (double)x[h] * (double)W1[h * 4 * H_ + j];
    hid[j] = (float)fmax(a, 0.0);
  }
  __syncthreads();
  double o = (double)b2[t];
  for (int j = 0; j < 4 * H_; j++) o += (double)hid[j] * (double)W2[j * H_ + t];
  double r = (double)x[t] + o;
  double mean = block_sum128d(r, red) * (1.0 / H_);
  double d0 = r - mean;
  double var = block_sum128d(d0 * d0, red) * (1.0 / H_);
  double y = d0 / sqrt(var + 1e-6);
  y *= (double)mask[node];
  hV[(size_t)node * H_ + t] = (float)y;
}

// ---------------- output: log_softmax(hV @ W_out + b_out), fp32 out ----------------
__global__ __launch_bounds__(64) void out_kernel(const float* __restrict__ hV,
    const float* __restrict__ Wout, const float* __restrict__ bout, float* __restrict__ out) {
  int node = blockIdx.x, t = threadIdx.x;
  __shared__ float x[H_];
  __shared__ double lg[V_];
  __shared__ double lse;
  x[t] = hV[(size_t)node * H_ + t];
  x[t + 64] = hV[(size_t)node * H_ + t + 64];
  __syncthreads();
  if (t < V_) {
    double a = (double)bout[t];
    for (int h = 0; h < H_; h++) a += (double)x[h] * (double)Wout[h * V_ + t];
    lg[t] = a;
  }
  __syncthreads();
  if (t == 0) {
    double mx = -1e300;
    for (int v = 0; v < V_; v++) mx = fmax(mx, lg[v]);
    double s = 0.0;
    for (int v = 0; v < V_; v++) s += exp(lg[v] - mx);
    lse = mx + log(s);
  }
  __syncthreads();
  if (t < V_) out[(size_t)node * V_ + t] = (float)(lg[t] - lse);
}

// ---------------- host ----------------
extern "C" void kernel_launch(void* const* d_in, const int* in_sizes, int n_in,
                              void* d_out, int out_size, void* d_ws, size_t ws_size,
                              hipStream_t stream) {
  const float* X    = (const float*)d_in[0];
  const float* mask = (const float*)d_in[1];
  const int*   S    = (const int*)d_in[2];
  const float* Wfn  = (const float*)d_in[3];
  const float* bfn  = (const float*)d_in[4];
  const float* Wfe  = (const float*)d_in[5];
  const float* bfe  = (const float*)d_in[6];
  const float* Wv   = (const float*)d_in[7];
  const float* bv   = (const float*)d_in[8];
  const float* We   = (const float*)d_in[9];
  const float* be   = (const float*)d_in[10];
  const float* Ws   = (const float*)d_in[11];
  const float* eWQ  = (const float*)d_in[12];
  const float* eWK  = (const float*)d_in[13];
  const float* eWV  = (const float*)d_in[14];
  const float* eWO  = (const float*)d_in[15];
  const float* eW1  = (const float*)d_in[16];
  const float* eb1  = (const float*)d_in[17];
  const float* eW2  = (const float*)d_in[18];
  const float* eb2  = (const float*)d_in[19];
  const float* dWQ  = (const float*)d_in[20];
  const float* dWK  = (const float*)d_in[21];
  const float* dWV  = (const float*)d_in[22];
  const float* dWO  = (const float*)d_in[23];
  const float* dW1  = (const float*)d_in[24];
  const float* db1  = (const float*)d_in[25];
  const float* dW2  = (const float*)d_in[26];
  const float* db2  = (const float*)d_in[27];
  const float* Wout = (const float*)d_in[28];
  const float* bout = (const float*)d_in[29];
  float* out = (float*)d_out;

  char* w = (char*)d_ws;
  int*    eidx = (int*)w;     w += (size_t)BN_ * K_ * 4;
  float*  dnb  = (float*)w;   w += (size_t)BN_ * K_ * 4;
  double* vf   = (double*)w;  w += (size_t)BN_ * 6 * 8;
  float*  hS   = (float*)w;   w += (size_t)BN_ * H_ * 4;
  float*  hVa  = (float*)w;   w += (size_t)BN_ * H_ * 4;
  float*  hVb  = (float*)w;   w += (size_t)BN_ * H_ * 4;
  float*  hVc  = (float*)w;   w += (size_t)BN_ * H_ * 4;
  float*  hE   = (float*)w;   w += (size_t)BN_ * K_ * H_ * 4;

  topk_kernel<<<BN_, 256, 0, stream>>>(X, mask, eidx, dnb);
  dihedral_kernel<<<(BN_ + 255) / 256, 256, 0, stream>>>(X, vf);
  node_embed_kernel<<<BN_, H_, 0, stream>>>(vf, Wfn, bfn, Wv, bv, hVa);
  edge_embed_kernel<<<BN_ * K_, H_, 0, stream>>>(eidx, dnb, Wfe, bfe, We, be, hE);
  hs_kernel<<<(BN_ * H_ + 255) / 256, 256, 0, stream>>>(S, Ws, hS);

  // encoder: a->b, b->a, a->b
  float* cur = hVa; float* nxt = hVb;
  for (int l = 0; l < 3; l++) {
    attn_kernel<2, true><<<BN_, H_, 0, stream>>>(cur, hE, nullptr, nullptr, eidx, mask,
        eWQ + (size_t)l * H_ * H_, eWK + (size_t)l * 2 * H_ * H_,
        eWV + (size_t)l * 2 * H_ * H_, eWO + (size_t)l * H_ * H_, nxt);
    ffn_kernel<<<BN_, H_, 0, stream>>>(nxt, mask,
        eW1 + (size_t)l * H_ * 4 * H_, eb1 + (size_t)l * 4 * H_,
        eW2 + (size_t)l * 4 * H_ * H_, eb2 + (size_t)l * H_);
    float* tmp = cur; cur = nxt; nxt = tmp;
  }
  float* henc = cur;  // = hVb
  // decoder: henc->a, a->c, c->a (henc preserved)
  float* din = henc;
  float* douts[3] = { hVa, hVc, hVa };
  for (int l = 0; l < 3; l++) {
    attn_kernel<3, false><<<BN_, H_, 0, stream>>>(din, hE, hS, henc, eidx, mask,
        dWQ + (size_t)l * H_ * H_, dWK + (size_t)l * 3 * H_ * H_,
        dWV + (size_t)l * 3 * H_ * H_, dWO + (size_t)l * H_ * H_, douts[l]);
    ffn_kernel<<<BN_, H_, 0, stream>>>(douts[l], mask,
        dW1 + (size_t)l * H_ * 4 * H_, db1 + (size_t)l * 4 * H_,
        dW2 + (size_t)l * 4 * H_ * H_, db2 + (size_t)l * H_);
    din = douts[l];
  }
  out_kernel<<<BN_, 64, 0, stream>>>(din, Wout, bout, out);
}

// Round 9
// 6750.916 us; speedup vs baseline: 2.6246x; 2.6246x over previous
//
#include <hip/hip_runtime.h>
#include <hip/hip_bf16.h>
#include <math.h>

#define DEVFN __device__ __forceinline__

constexpr int B_ = 16, N_ = 512, K_ = 30, H_ = 128;
constexpr int NH_ = 4, V_ = 20;
constexpr int BN_ = B_ * N_;
constexpr float NEG_INF_ = -3.4028235e38f;

DEVFN double block_sum128d(double v, double* sbuf) {
  int t = threadIdx.x;
  sbuf[t] = v; __syncthreads();
  #pragma unroll
  for (int s = 64; s > 0; s >>= 1) {
    if (t < s) sbuf[t] += sbuf[t + s];
    __syncthreads();
  }
  double r = sbuf[0];
  __syncthreads();
  return r;
}

DEVFN float block_sum128f(float v, float* sbuf) {
  int t = threadIdx.x;
  sbuf[t] = v; __syncthreads();
  #pragma unroll
  for (int s = 64; s > 0; s >>= 1) {
    if (t < s) sbuf[t] += sbuf[t + s];
    __syncthreads();
  }
  float r = sbuf[0];
  __syncthreads();
  return r;
}

// ---------------- top-K neighbors: distances BIT-EXACT to plain numpy float32 ----------------
// DO NOT TOUCH: bit-exact __f*_rn distance + higher-index tie-break is what makes the
// neighbor sets match the np reference at exact ties (bf16-valued coords) — R8 fix.
__global__ __launch_bounds__(256) void topk_kernel(const float* __restrict__ X,
    const float* __restrict__ mask, int* __restrict__ E_idx, float* __restrict__ Dnb) {
  __shared__ float xs[N_ * 3];
  __shared__ float ds[N_];
  __shared__ float fred[256];
  __shared__ unsigned long long kred[256];
  int b = blockIdx.x / N_, i = blockIdx.x % N_;
  int t = threadIdx.x;
  for (int j = t; j < N_; j += 256) {
    const float* p = X + ((size_t)(b * N_ + j) * 4 + 1) * 3;  // CA atom
    xs[j * 3 + 0] = p[0]; xs[j * 3 + 1] = p[1]; xs[j * 3 + 2] = p[2];
  }
  __syncthreads();
  float xi0 = xs[i * 3], xi1 = xs[i * 3 + 1], xi2 = xs[i * 3 + 2];
  float mi = mask[b * N_ + i];
  float lmax = -3.4e38f;
  for (int j = t; j < N_; j += 256) {
    float dx = __fsub_rn(xi0, xs[j * 3]);
    float dy = __fsub_rn(xi1, xs[j * 3 + 1]);
    float dz = __fsub_rn(xi2, xs[j * 3 + 2]);
    float m2 = __fmul_rn(mi, mask[b * N_ + j]);
    float s = __fadd_rn(__fadd_rn(__fadd_rn(__fmul_rn(dx, dx), __fmul_rn(dy, dy)),
                                  __fmul_rn(dz, dz)), 1e-6f);
    float D = __fmul_rn(m2, __fsqrt_rn(s));
    ds[j] = D;
    lmax = fmaxf(lmax, D);
  }
  fred[t] = lmax; __syncthreads();
  for (int s = 128; s > 0; s >>= 1) { if (t < s) fred[t] = fmaxf(fred[t], fred[t + s]); __syncthreads(); }
  float Dmax = fred[0]; __syncthreads();
  for (int j = t; j < N_; j += 256) {
    float m2 = __fmul_rn(mi, mask[b * N_ + j]);
    ds[j] = __fadd_rn(ds[j], __fmul_rn(__fsub_rn(1.f, m2), Dmax));
  }
  __syncthreads();
  // extract K smallest; equal distances -> HIGHER index first
  for (int kk = 0; kk < K_; kk++) {
    unsigned long long best = ~0ull;
    for (int j = t; j < N_; j += 256) {
      unsigned long long key = (((unsigned long long)__float_as_uint(ds[j])) << 32)
                             | (unsigned)(N_ - 1 - j);
      if (key < best) best = key;
    }
    kred[t] = best; __syncthreads();
    for (int s = 128; s > 0; s >>= 1) { if (t < s && kred[t + s] < kred[t]) kred[t] = kred[t + s]; __syncthreads(); }
    if (t == 0) {
      unsigned long long k0 = kred[0];
      int j = N_ - 1 - (int)(k0 & 0xffffffffull);
      E_idx[blockIdx.x * K_ + kk] = j;
      Dnb[blockIdx.x * K_ + kk] = __uint_as_float((unsigned)(k0 >> 32));
      ds[j] = 3.4028235e38f;
    }
    __syncthreads();
  }
}

// ---------------- dihedral features (1 thread / node), double ----------------
DEVFN void load_atomd(const float* X, int b, int m, double* p) {
  const float* q = X + ((size_t)(b * N_ + m / 3) * 4 + (m % 3)) * 3;
  p[0] = (double)q[0]; p[1] = (double)q[1]; p[2] = (double)q[2];
}
DEVFN void cross3d(const double* a, const double* b, double* c) {
  c[0] = a[1] * b[2] - a[2] * b[1];
  c[1] = a[2] * b[0] - a[0] * b[2];
  c[2] = a[0] * b[1] - a[1] * b[0];
}
DEVFN void norm3d(double* v) {
  double n = sqrt(v[0] * v[0] + v[1] * v[1] + v[2] * v[2]) + 1e-7;
  v[0] /= n; v[1] /= n; v[2] /= n;
}
__global__ __launch_bounds__(256) void dihedral_kernel(const float* __restrict__ X, double* __restrict__ Vf) {
  int idx = blockIdx.x * blockDim.x + threadIdx.x;
  if (idx >= BN_) return;
  int b = idx / N_, n = idx % N_;
  double cs[3], sn[3];
  for (int s = 0; s < 3; s++) {
    int p = 3 * n + s;
    double a = 0.0;
    if (p >= 1 && p <= 3 * N_ - 3) {
      int tt = p - 1;
      double u[3][3];
      double prev[3], cur[3];
      load_atomd(X, b, tt, prev);
      for (int q = 0; q < 3; q++) {
        load_atomd(X, b, tt + q + 1, cur);
        double d0 = cur[0] - prev[0], d1 = cur[1] - prev[1], d2 = cur[2] - prev[2];
        double nr = sqrt(d0 * d0 + d1 * d1 + d2 * d2) + 1e-7;
        u[q][0] = d0 / nr; u[q][1] = d1 / nr; u[q][2] = d2 / nr;
        prev[0] = cur[0]; prev[1] = cur[1]; prev[2] = cur[2];
      }
      double n2v[3], n1v[3];
      cross3d(u[0], u[1], n2v); norm3d(n2v);
      cross3d(u[1], u[2], n1v); norm3d(n1v);
      double cd = n2v[0] * n1v[0] + n2v[1] * n1v[1] + n2v[2] * n1v[2];
      cd = fmin(fmax(cd, -1.0 + 1e-7), 1.0 - 1e-7);
      double dt = u[0][0] * n1v[0] + u[0][1] * n1v[1] + u[0][2] * n1v[2];
      double sg = (dt > 0.0) ? 1.0 : ((dt < 0.0) ? -1.0 : 0.0);
      a = sg * acos(cd);
    }
    cs[s] = cos(a); sn[s] = sin(a);
  }
  double* o = Vf + (size_t)idx * 6;
  o[0] = cs[0]; o[1] = cs[1]; o[2] = cs[2]; o[3] = sn[0]; o[4] = sn[1]; o[5] = sn[2];
}

// ---------------- node embed: hV = LN(V@Wfn+bfn) @ Wv + bv ----------------
__global__ __launch_bounds__(H_) void node_embed_kernel(const double* __restrict__ Vf,
    const float* __restrict__ Wfn, const float* __restrict__ bfn,
    const float* __restrict__ Wv, const float* __restrict__ bv, float* __restrict__ hV) {
  int node = blockIdx.x, t = threadIdx.x;
  __shared__ double v6[6];
  __shared__ double t1[H_];
  __shared__ double red[H_];
  if (t < 6) v6[t] = Vf[(size_t)node * 6 + t];
  __syncthreads();
  double acc = (double)bfn[t];
  for (int f = 0; f < 6; f++) acc += v6[f] * (double)Wfn[f * H_ + t];
  double mean = block_sum128d(acc, red) * (1.0 / H_);
  double d0 = acc - mean;
  double var = block_sum128d(d0 * d0, red) * (1.0 / H_);
  t1[t] = d0 / sqrt(var + 1e-6);
  __syncthreads();
  double o = (double)bv[t];
  for (int j = 0; j < H_; j++) o += t1[j] * (double)Wv[j * H_ + t];
  hV[(size_t)node * H_ + t] = (float)o;
}

// ---------------- edge embed: hE = LN(E@Wfe+bfe) @ We + be ----------------
__global__ __launch_bounds__(H_) void edge_embed_kernel(const int* __restrict__ E_idx,
    const float* __restrict__ Dnb, const float* __restrict__ Wfe, const float* __restrict__ bfe,
    const float* __restrict__ We, const float* __restrict__ be, float* __restrict__ hE) {
  int e = blockIdx.x, t = threadIdx.x;
  int n = (e / K_) % N_;
  __shared__ double feat[32];
  __shared__ double t1[H_];
  __shared__ double red[H_];
  if (t < 32) {
    double v;
    int j = E_idx[e];
    if (t < 16) {
      int jj = (t < 8) ? t : (t - 8);
      double freq = exp(-log(10000.0) * (2.0 * jj) / 16.0);
      double ang = (double)(j - n) * freq;
      v = (t < 8) ? cos(ang) : sin(ang);
    } else {
      int r = t - 16;
      double mu = 20.0 * (double)r / 15.0;
      double z = ((double)Dnb[e] - mu) / 1.25;
      v = exp(-z * z);
    }
    feat[t] = v;
  }
  __syncthreads();
  double acc = (double)bfe[t];
  for (int f = 0; f < 32; f++) acc += feat[f] * (double)Wfe[f * H_ + t];
  double mean = block_sum128d(acc, red) * (1.0 / H_);
  double d0 = acc - mean;
  double var = block_sum128d(d0 * d0, red) * (1.0 / H_);
  t1[t] = d0 / sqrt(var + 1e-6);
  __syncthreads();
  double o = (double)be[t];
  for (int j = 0; j < H_; j++) o += t1[j] * (double)We[j * H_ + t];
  hE[(size_t)e * H_ + t] = (float)o;
}

// ---------------- h_S = Ws[S] ----------------
__global__ __launch_bounds__(256) void hs_kernel(const int* __restrict__ S,
    const float* __restrict__ Ws, float* __restrict__ hS) {
  int idx = blockIdx.x * 256 + threadIdx.x;
  if (idx >= BN_ * H_) return;
  int node = idx / H_, h = idx % H_;
  hS[idx] = Ws[(size_t)S[node] * H_ + h];
}

// ---------------- fused graph attention + residual LN (fp32, KT-tiled) ----------------
// XC = #H-chunks in x (2 encoder, 3 decoder). KT=15 neighbors per tile: weight slab
// (WK/WV) is streamed 2x instead of 30x; kv/vv accumulators live in VGPRs.
template<int XC, bool ENC>
__global__ __launch_bounds__(H_) void attn_kernel(const float* __restrict__ hV_in,
    const float* __restrict__ hE, const float* __restrict__ hS, const float* __restrict__ hVenc,
    const int* __restrict__ E_idx, const float* __restrict__ mask,
    const float* __restrict__ WQ, const float* __restrict__ WK,
    const float* __restrict__ WV, const float* __restrict__ WO,
    float* __restrict__ hV_out) {
  constexpr int XCH = XC * H_;
  constexpr int KT = 15;
  const int node = blockIdx.x;
  const int b = node / N_, n = node % N_;
  const int t = threadIdx.x;
  const int head = t >> 5, lane32 = t & 31;
  __shared__ __attribute__((aligned(16))) float x0[H_];
  __shared__ __attribute__((aligned(16))) float xk[KT * XCH];
  __shared__ __attribute__((aligned(16))) float vbuf[K_ * H_];
  __shared__ __attribute__((aligned(16))) float ob[H_];
  __shared__ float sc[NH_ * K_];
  __shared__ float att[NH_ * K_];
  __shared__ float red[H_];
  __shared__ int nbs[K_];

  x0[t] = hV_in[(size_t)node * H_ + t];
  if (t < K_) nbs[t] = E_idx[node * K_ + t];
  __syncthreads();

  // Q projection (result stays in a register; only this thread uses it)
  float qreg = 0.f;
  for (int j4 = 0; j4 < H_ / 4; j4++) {
    float4 xv = ((const float4*)x0)[j4];
    int j = j4 * 4;
    qreg = fmaf(xv.x, WQ[(j + 0) * H_ + t],
           fmaf(xv.y, WQ[(j + 1) * H_ + t],
           fmaf(xv.z, WQ[(j + 2) * H_ + t],
           fmaf(xv.w, WQ[(j + 3) * H_ + t], qreg))));
  }
  float mi = mask[b * N_ + n];

  for (int kt = 0; kt < K_; kt += KT) {
    // stage xk rows for KT neighbors
    #pragma unroll
    for (int u = 0; u < KT; u++) {
      int k = kt + u;
      int nb = nbs[k];
      size_t nbg = (size_t)(b * N_ + nb) * H_;
      float c0 = hE[(size_t)(node * K_ + k) * H_ + t];
      if (ENC) {
        xk[u * XCH + t] = c0;
        xk[u * XCH + H_ + t] = hV_in[nbg + t];
      } else {
        float ar = (nb < n) ? 1.f : 0.f;
        float bw = mi * ar, fw = mi * (1.f - ar);
        xk[u * XCH + t] = mi * c0;
        xk[u * XCH + H_ + t] = bw * hS[nbg + t];
        xk[u * XCH + 2 * H_ + t] = bw * hV_in[nbg + t] + fw * hVenc[nbg + t];
      }
    }
    __syncthreads();

    float kv[KT], vv[KT];
    #pragma unroll
    for (int u = 0; u < KT; u++) { kv[u] = 0.f; vv[u] = 0.f; }
    for (int j4 = 0; j4 < XCH / 4; j4++) {
      int j = j4 * 4;
      float wk0 = WK[(j + 0) * H_ + t], wk1 = WK[(j + 1) * H_ + t];
      float wk2 = WK[(j + 2) * H_ + t], wk3 = WK[(j + 3) * H_ + t];
      float wv0 = WV[(j + 0) * H_ + t], wv1 = WV[(j + 1) * H_ + t];
      float wv2 = WV[(j + 2) * H_ + t], wv3 = WV[(j + 3) * H_ + t];
      #pragma unroll
      for (int u = 0; u < KT; u++) {
        float4 xv = *((const float4*)(xk + u * XCH + j));
        kv[u] = fmaf(xv.x, wk0, fmaf(xv.y, wk1, fmaf(xv.z, wk2, fmaf(xv.w, wk3, kv[u]))));
        vv[u] = fmaf(xv.x, wv0, fmaf(xv.y, wv1, fmaf(xv.z, wv2, fmaf(xv.w, wv3, vv[u]))));
      }
    }
    #pragma unroll
    for (int u = 0; u < KT; u++) {
      int k = kt + u;
      vbuf[k * H_ + t] = vv[u];
      float prod = qreg * kv[u];
      #pragma unroll
      for (int off = 16; off > 0; off >>= 1) prod += __shfl_xor(prod, off, 32);
      if (lane32 == 0) {
        float lg = prod * 0.17677669529663687f;  // 1/sqrt(32)
        if (ENC) {
          float m2 = mi * mask[b * N_ + nbs[k]];
          sc[head * K_ + k] = (m2 > 0.f) ? lg : NEG_INF_;
        } else {
          sc[head * K_ + k] = lg;
        }
      }
    }
    __syncthreads();  // protects xk reuse + sc visibility
  }

  if (t < NH_) {
    float mx = -3.4e38f;
    for (int k = 0; k < K_; k++) mx = fmaxf(mx, sc[t * K_ + k]);
    float s = 0.f;
    for (int k = 0; k < K_; k++) { float ev = expf(sc[t * K_ + k] - mx); att[t * K_ + k] = ev; s += ev; }
    float inv = 1.f / s;
    for (int k = 0; k < K_; k++) att[t * K_ + k] *= inv;
  }
  __syncthreads();
  if (ENC && t < K_) {
    float m2 = mi * mask[b * N_ + nbs[t]];
    for (int hh = 0; hh < NH_; hh++) att[hh * K_ + t] *= m2;
  }
  __syncthreads();
  float o = 0.f;
  for (int k = 0; k < K_; k++) o = fmaf(att[head * K_ + k], vbuf[k * H_ + t], o);
  ob[t] = o; __syncthreads();
  float dh = 0.f;
  for (int j4 = 0; j4 < H_ / 4; j4++) {
    float4 ov = ((const float4*)ob)[j4];
    int j = j4 * 4;
    dh = fmaf(ov.x, WO[(j + 0) * H_ + t],
         fmaf(ov.y, WO[(j + 1) * H_ + t],
         fmaf(ov.z, WO[(j + 2) * H_ + t],
         fmaf(ov.w, WO[(j + 3) * H_ + t], dh))));
  }
  float r = x0[t] + dh;
  float mean = block_sum128f(r, red) * (1.f / H_);
  float d0 = r - mean;
  float var = block_sum128f(d0 * d0, red) * (1.f / H_);
  hV_out[(size_t)node * H_ + t] = d0 * rsqrtf(var + 1e-6f);
}

// ---------------- FFN + residual LN + node mask (in-place, fp32 vectorized) ----------------
__global__ __launch_bounds__(H_) void ffn_kernel(float* __restrict__ hV, const float* __restrict__ mask,
    const float* __restrict__ W1, const float* __restrict__ b1,
    const float* __restrict__ W2, const float* __restrict__ b2) {
  int node = blockIdx.x, t = threadIdx.x;
  __shared__ __attribute__((aligned(16))) float x[H_];
  __shared__ __attribute__((aligned(16))) float hid[4 * H_];
  __shared__ float red[H_];
  x[t] = hV[(size_t)node * H_ + t];
  __syncthreads();
  #pragma unroll
  for (int c = 0; c < 4; c++) {
    float a = b1[c * H_ + t];
    for (int h4 = 0; h4 < H_ / 4; h4++) {
      float4 xv = ((const float4*)x)[h4];
      int h = h4 * 4;
      a = fmaf(xv.x, W1[(h + 0) * 4 * H_ + c * H_ + t],
          fmaf(xv.y, W1[(h + 1) * 4 * H_ + c * H_ + t],
          fmaf(xv.z, W1[(h + 2) * 4 * H_ + c * H_ + t],
          fmaf(xv.w, W1[(h + 3) * 4 * H_ + c * H_ + t], a))));
    }
    hid[c * H_ + t] = fmaxf(a, 0.f);
  }
  __syncthreads();
  float o = b2[t];
  for (int j4 = 0; j4 < (4 * H_) / 4; j4++) {
    float4 hv = ((const float4*)hid)[j4];
    int j = j4 * 4;
    o = fmaf(hv.x, W2[(j + 0) * H_ + t],
        fmaf(hv.y, W2[(j + 1) * H_ + t],
        fmaf(hv.z, W2[(j + 2) * H_ + t],
        fmaf(hv.w, W2[(j + 3) * H_ + t], o))));
  }
  float r = x[t] + o;
  float mean = block_sum128f(r, red) * (1.f / H_);
  float d0 = r - mean;
  float var = block_sum128f(d0 * d0, red) * (1.f / H_);
  float y = d0 * rsqrtf(var + 1e-6f);
  y *= mask[node];
  hV[(size_t)node * H_ + t] = y;
}

// ---------------- output: log_softmax(hV @ W_out + b_out), fp32 out ----------------
__global__ __launch_bounds__(64) void out_kernel(const float* __restrict__ hV,
    const float* __restrict__ Wout, const float* __restrict__ bout, float* __restrict__ out) {
  int node = blockIdx.x, t = threadIdx.x;
  __shared__ float x[H_];
  __shared__ double lg[V_];
  __shared__ double lse;
  x[t] = hV[(size_t)node * H_ + t];
  x[t + 64] = hV[(size_t)node * H_ + t + 64];
  __syncthreads();
  if (t < V_) {
    double a = (double)bout[t];
    for (int h = 0; h < H_; h++) a += (double)x[h] * (double)Wout[h * V_ + t];
    lg[t] = a;
  }
  __syncthreads();
  if (t == 0) {
    double mx = -1e300;
    for (int v = 0; v < V_; v++) mx = fmax(mx, lg[v]);
    double s = 0.0;
    for (int v = 0; v < V_; v++) s += exp(lg[v] - mx);
    lse = mx + log(s);
  }
  __syncthreads();
  if (t < V_) out[(size_t)node * V_ + t] = (float)(lg[t] - lse);
}

// ---------------- host ----------------
extern "C" void kernel_launch(void* const* d_in, const int* in_sizes, int n_in,
                              void* d_out, int out_size, void* d_ws, size_t ws_size,
                              hipStream_t stream) {
  const float* X    = (const float*)d_in[0];
  const float* mask = (const float*)d_in[1];
  const int*   S    = (const int*)d_in[2];
  const float* Wfn  = (const float*)d_in[3];
  const float* bfn  = (const float*)d_in[4];
  const float* Wfe  = (const float*)d_in[5];
  const float* bfe  = (const float*)d_in[6];
  const float* Wv   = (const float*)d_in[7];
  const float* bv   = (const float*)d_in[8];
  const float* We   = (const float*)d_in[9];
  const float* be   = (const float*)d_in[10];
  const float* Ws   = (const float*)d_in[11];
  const float* eWQ  = (const float*)d_in[12];
  const float* eWK  = (const float*)d_in[13];
  const float* eWV  = (const float*)d_in[14];
  const float* eWO  = (const float*)d_in[15];
  const float* eW1  = (const float*)d_in[16];
  const float* eb1  = (const float*)d_in[17];
  const float* eW2  = (const float*)d_in[18];
  const float* eb2  = (const float*)d_in[19];
  const float* dWQ  = (const float*)d_in[20];
  const float* dWK  = (const float*)d_in[21];
  const float* dWV  = (const float*)d_in[22];
  const float* dWO  = (const float*)d_in[23];
  const float* dW1  = (const float*)d_in[24];
  const float* db1  = (const float*)d_in[25];
  const float* dW2  = (const float*)d_in[26];
  const float* db2  = (const float*)d_in[27];
  const float* Wout = (const float*)d_in[28];
  const float* bout = (const float*)d_in[29];
  float* out = (float*)d_out;

  char* w = (char*)d_ws;
  int*    eidx = (int*)w;     w += (size_t)BN_ * K_ * 4;
  float*  dnb  = (float*)w;   w += (size_t)BN_ * K_ * 4;
  double* vf   = (double*)w;  w += (size_t)BN_ * 6 * 8;
  float*  hS   = (float*)w;   w += (size_t)BN_ * H_ * 4;
  float*  hVa  = (float*)w;   w += (size_t)BN_ * H_ * 4;
  float*  hVb  = (float*)w;   w += (size_t)BN_ * H_ * 4;
  float*  hVc  = (float*)w;   w += (size_t)BN_ * H_ * 4;
  float*  hE   = (float*)w;   w += (size_t)BN_ * K_ * H_ * 4;

  topk_kernel<<<BN_, 256, 0, stream>>>(X, mask, eidx, dnb);
  dihedral_kernel<<<(BN_ + 255) / 256, 256, 0, stream>>>(X, vf);
  node_embed_kernel<<<BN_, H_, 0, stream>>>(vf, Wfn, bfn, Wv, bv, hVa);
  edge_embed_kernel<<<BN_ * K_, H_, 0, stream>>>(eidx, dnb, Wfe, bfe, We, be, hE);
  hs_kernel<<<(BN_ * H_ + 255) / 256, 256, 0, stream>>>(S, Ws, hS);

  // encoder: a->b, b->a, a->b
  float* cur = hVa; float* nxt = hVb;
  for (int l = 0; l < 3; l++) {
    attn_kernel<2, true><<<BN_, H_, 0, stream>>>(cur, hE, nullptr, nullptr, eidx, mask,
        eWQ + (size_t)l * H_ * H_, eWK + (size_t)l * 2 * H_ * H_,
        eWV + (size_t)l * 2 * H_ * H_, eWO + (size_t)l * H_ * H_, nxt);
    ffn_kernel<<<BN_, H_, 0, stream>>>(nxt, mask,
        eW1 + (size_t)l * H_ * 4 * H_, eb1 + (size_t)l * 4 * H_,
        eW2 + (size_t)l * 4 * H_ * H_, eb2 + (size_t)l * H_);
    float* tmp = cur; cur = nxt; nxt = tmp;
  }
  float* henc = cur;  // = hVb
  // decoder: henc->a, a->c, c->a (henc preserved)
  float* din = henc;
  float* douts[3] = { hVa, hVc, hVa };
  for (int l = 0; l < 3; l++) {
    attn_kernel<3, false><<<BN_, H_, 0, stream>>>(din, hE, hS, henc, eidx, mask,
        dWQ + (size_t)l * H_ * H_, dWK + (size_t)l * 3 * H_ * H_,
        dWV + (size_t)l * 3 * H_ * H_, dWO + (size_t)l * H_ * H_, douts[l]);
    ffn_kernel<<<BN_, H_, 0, stream>>>(douts[l], mask,
        dW1 + (size_t)l * H_ * 4 * H_, db1 + (size_t)l * 4 * H_,
        dW2 + (size_t)l * 4 * H_ * H_, db2 + (size_t)l * H_);
    din = douts[l];
  }
  out_kernel<<<BN_, 64, 0, stream>>>(din, Wout, bout, out);
}

// Round 10
// 5786.588 us; speedup vs baseline: 3.0620x; 1.1666x over previous
//
#include <hip/hip_runtime.h>
#include <hip/hip_bf16.h>
#include <math.h>

#define DEVFN __device__ __forceinline__

constexpr int B_ = 16, N_ = 512, K_ = 30, H_ = 128;
constexpr int NH_ = 4, V_ = 20;
constexpr int BN_ = B_ * N_;
constexpr float NEG_INF_ = -3.4028235e38f;

DEVFN float block_sum128f(float v, float* sbuf) {
  int t = threadIdx.x;
  sbuf[t] = v; __syncthreads();
  #pragma unroll
  for (int s = 64; s > 0; s >>= 1) {
    if (t < s) sbuf[t] += sbuf[t + s];
    __syncthreads();
  }
  float r = sbuf[0];
  __syncthreads();
  return r;
}

// ---------------- top-K neighbors: distances BIT-EXACT to plain numpy float32 ----------------
// DO NOT TOUCH: bit-exact __f*_rn distance + higher-index tie-break is what makes the
// neighbor sets match the np reference at exact ties (bf16-valued coords) — R8 fix.
__global__ __launch_bounds__(256) void topk_kernel(const float* __restrict__ X,
    const float* __restrict__ mask, int* __restrict__ E_idx, float* __restrict__ Dnb) {
  __shared__ float xs[N_ * 3];
  __shared__ float ds[N_];
  __shared__ float fred[256];
  __shared__ unsigned long long kred[256];
  int b = blockIdx.x / N_, i = blockIdx.x % N_;
  int t = threadIdx.x;
  for (int j = t; j < N_; j += 256) {
    const float* p = X + ((size_t)(b * N_ + j) * 4 + 1) * 3;  // CA atom
    xs[j * 3 + 0] = p[0]; xs[j * 3 + 1] = p[1]; xs[j * 3 + 2] = p[2];
  }
  __syncthreads();
  float xi0 = xs[i * 3], xi1 = xs[i * 3 + 1], xi2 = xs[i * 3 + 2];
  float mi = mask[b * N_ + i];
  float lmax = -3.4e38f;
  for (int j = t; j < N_; j += 256) {
    float dx = __fsub_rn(xi0, xs[j * 3]);
    float dy = __fsub_rn(xi1, xs[j * 3 + 1]);
    float dz = __fsub_rn(xi2, xs[j * 3 + 2]);
    float m2 = __fmul_rn(mi, mask[b * N_ + j]);
    float s = __fadd_rn(__fadd_rn(__fadd_rn(__fmul_rn(dx, dx), __fmul_rn(dy, dy)),
                                  __fmul_rn(dz, dz)), 1e-6f);
    float D = __fmul_rn(m2, __fsqrt_rn(s));
    ds[j] = D;
    lmax = fmaxf(lmax, D);
  }
  fred[t] = lmax; __syncthreads();
  for (int s = 128; s > 0; s >>= 1) { if (t < s) fred[t] = fmaxf(fred[t], fred[t + s]); __syncthreads(); }
  float Dmax = fred[0]; __syncthreads();
  for (int j = t; j < N_; j += 256) {
    float m2 = __fmul_rn(mi, mask[b * N_ + j]);
    ds[j] = __fadd_rn(ds[j], __fmul_rn(__fsub_rn(1.f, m2), Dmax));
  }
  __syncthreads();
  // extract K smallest; equal distances -> HIGHER index first
  for (int kk = 0; kk < K_; kk++) {
    unsigned long long best = ~0ull;
    for (int j = t; j < N_; j += 256) {
      unsigned long long key = (((unsigned long long)__float_as_uint(ds[j])) << 32)
                             | (unsigned)(N_ - 1 - j);
      if (key < best) best = key;
    }
    kred[t] = best; __syncthreads();
    for (int s = 128; s > 0; s >>= 1) { if (t < s && kred[t + s] < kred[t]) kred[t] = kred[t + s]; __syncthreads(); }
    if (t == 0) {
      unsigned long long k0 = kred[0];
      int j = N_ - 1 - (int)(k0 & 0xffffffffull);
      E_idx[blockIdx.x * K_ + kk] = j;
      Dnb[blockIdx.x * K_ + kk] = __uint_as_float((unsigned)(k0 >> 32));
      ds[j] = 3.4028235e38f;
    }
    __syncthreads();
  }
}

// ---------------- dihedral features (1 thread / node), fp32 ----------------
DEVFN void load_atom(const float* X, int b, int m, float* p) {
  const float* q = X + ((size_t)(b * N_ + m / 3) * 4 + (m % 3)) * 3;
  p[0] = q[0]; p[1] = q[1]; p[2] = q[2];
}
DEVFN void cross3(const float* a, const float* b, float* c) {
  c[0] = a[1] * b[2] - a[2] * b[1];
  c[1] = a[2] * b[0] - a[0] * b[2];
  c[2] = a[0] * b[1] - a[1] * b[0];
}
DEVFN void norm3(float* v) {
  float n = sqrtf(v[0] * v[0] + v[1] * v[1] + v[2] * v[2]) + 1e-7f;
  v[0] /= n; v[1] /= n; v[2] /= n;
}
__global__ __launch_bounds__(256) void dihedral_kernel(const float* __restrict__ X, float* __restrict__ Vf) {
  int idx = blockIdx.x * blockDim.x + threadIdx.x;
  if (idx >= BN_) return;
  int b = idx / N_, n = idx % N_;
  float cs[3], sn[3];
  for (int s = 0; s < 3; s++) {
    int p = 3 * n + s;
    float a = 0.f;
    if (p >= 1 && p <= 3 * N_ - 3) {
      int tt = p - 1;
      float u[3][3], prev[3], cur[3];
      load_atom(X, b, tt, prev);
      for (int q = 0; q < 3; q++) {
        load_atom(X, b, tt + q + 1, cur);
        float d0 = cur[0] - prev[0], d1 = cur[1] - prev[1], d2 = cur[2] - prev[2];
        float nr = sqrtf(d0 * d0 + d1 * d1 + d2 * d2) + 1e-7f;
        u[q][0] = d0 / nr; u[q][1] = d1 / nr; u[q][2] = d2 / nr;
        prev[0] = cur[0]; prev[1] = cur[1]; prev[2] = cur[2];
      }
      float n2v[3], n1v[3];
      cross3(u[0], u[1], n2v); norm3(n2v);
      cross3(u[1], u[2], n1v); norm3(n1v);
      float cd = n2v[0] * n1v[0] + n2v[1] * n1v[1] + n2v[2] * n1v[2];
      cd = fminf(fmaxf(cd, -1.f + 1e-7f), 1.f - 1e-7f);
      float dt = u[0][0] * n1v[0] + u[0][1] * n1v[1] + u[0][2] * n1v[2];
      float sg = (dt > 0.f) ? 1.f : ((dt < 0.f) ? -1.f : 0.f);
      a = sg * acosf(cd);
    }
    cs[s] = cosf(a); sn[s] = sinf(a);
  }
  float* o = Vf + (size_t)idx * 6;
  o[0] = cs[0]; o[1] = cs[1]; o[2] = cs[2]; o[3] = sn[0]; o[4] = sn[1]; o[5] = sn[2];
}

// ---------------- node embed: hV = LN(V@Wfn+bfn) @ Wv + bv (fp32) ----------------
__global__ __launch_bounds__(H_) void node_embed_kernel(const float* __restrict__ Vf,
    const float* __restrict__ Wfn, const float* __restrict__ bfn,
    const float* __restrict__ Wv, const float* __restrict__ bv, float* __restrict__ hV) {
  int node = blockIdx.x, t = threadIdx.x;
  __shared__ float v6[6];
  __shared__ float t1[H_];
  __shared__ float red[H_];
  if (t < 6) v6[t] = Vf[(size_t)node * 6 + t];
  __syncthreads();
  float acc = bfn[t];
  for (int f = 0; f < 6; f++) acc = fmaf(v6[f], Wfn[f * H_ + t], acc);
  float mean = block_sum128f(acc, red) * (1.f / H_);
  float d0 = acc - mean;
  float var = block_sum128f(d0 * d0, red) * (1.f / H_);
  t1[t] = d0 * rsqrtf(var + 1e-6f);
  __syncthreads();
  float o = bv[t];
  for (int j = 0; j < H_; j++) o = fmaf(t1[j], Wv[j * H_ + t], o);
  hV[(size_t)node * H_ + t] = o;
}

// ---------------- edge embed: hE = LN(E@Wfe+bfe) @ We + be (fp32) ----------------
__global__ __launch_bounds__(H_) void edge_embed_kernel(const int* __restrict__ E_idx,
    const float* __restrict__ Dnb, const float* __restrict__ Wfe, const float* __restrict__ bfe,
    const float* __restrict__ We, const float* __restrict__ be, float* __restrict__ hE) {
  int e = blockIdx.x, t = threadIdx.x;
  int n = (e / K_) % N_;
  __shared__ float feat[32];
  __shared__ float t1[H_];
  __shared__ float red[H_];
  if (t < 32) {
    float v;
    int j = E_idx[e];
    if (t < 16) {
      int jj = (t < 8) ? t : (t - 8);
      float freq = expf(-logf(10000.f) * (2.f * jj) / 16.f);
      float ang = (float)(j - n) * freq;
      v = (t < 8) ? cosf(ang) : sinf(ang);
    } else {
      int r = t - 16;
      float mu = 20.f * (float)r / 15.f;
      float z = (Dnb[e] - mu) * (1.f / 1.25f);
      v = expf(-z * z);
    }
    feat[t] = v;
  }
  __syncthreads();
  float acc = bfe[t];
  for (int f = 0; f < 32; f++) acc = fmaf(feat[f], Wfe[f * H_ + t], acc);
  float mean = block_sum128f(acc, red) * (1.f / H_);
  float d0 = acc - mean;
  float var = block_sum128f(d0 * d0, red) * (1.f / H_);
  t1[t] = d0 * rsqrtf(var + 1e-6f);
  __syncthreads();
  float o = be[t];
  for (int j = 0; j < H_; j++) o = fmaf(t1[j], We[j * H_ + t], o);
  hE[(size_t)e * H_ + t] = o;
}

// ---------------- h_S = Ws[S] ----------------
__global__ __launch_bounds__(256) void hs_kernel(const int* __restrict__ S,
    const float* __restrict__ Ws, float* __restrict__ hS) {
  int idx = blockIdx.x * 256 + threadIdx.x;
  if (idx >= BN_ * H_) return;
  int node = idx / H_, h = idx % H_;
  hS[idx] = Ws[(size_t)S[node] * H_ + h];
}

// ---------------- fused graph attention + residual LN (fp32, KT=10 tiles, V in VGPRs) ----------------
// LDS ~18 KB -> ~8 blocks/CU (occupancy ~50%); V-rows kept in 30 per-thread registers.
template<int XC, bool ENC>
__global__ __launch_bounds__(H_) void attn_kernel(const float* __restrict__ hV_in,
    const float* __restrict__ hE, const float* __restrict__ hS, const float* __restrict__ hVenc,
    const int* __restrict__ E_idx, const float* __restrict__ mask,
    const float* __restrict__ WQ, const float* __restrict__ WK,
    const float* __restrict__ WV, const float* __restrict__ WO,
    float* __restrict__ hV_out) {
  constexpr int XCH = XC * H_;
  constexpr int KT = 10;
  const int node = blockIdx.x;
  const int b = node / N_, n = node % N_;
  const int t = threadIdx.x;
  const int head = t >> 5, lane32 = t & 31;
  __shared__ __attribute__((aligned(16))) float x0[H_];
  __shared__ __attribute__((aligned(16))) float xk[KT * XCH];
  __shared__ __attribute__((aligned(16))) float ob[H_];
  __shared__ float sc[NH_ * K_];
  __shared__ float att[NH_ * K_];
  __shared__ float red[H_];
  __shared__ int nbs[K_];

  x0[t] = hV_in[(size_t)node * H_ + t];
  if (t < K_) nbs[t] = E_idx[node * K_ + t];
  __syncthreads();

  // Q projection (register-resident)
  float qreg = 0.f;
  for (int j4 = 0; j4 < H_ / 4; j4++) {
    float4 xv = ((const float4*)x0)[j4];
    int j = j4 * 4;
    qreg = fmaf(xv.x, WQ[(j + 0) * H_ + t],
           fmaf(xv.y, WQ[(j + 1) * H_ + t],
           fmaf(xv.z, WQ[(j + 2) * H_ + t],
           fmaf(xv.w, WQ[(j + 3) * H_ + t], qreg))));
  }
  float mi = mask[b * N_ + n];

  float vvAll[K_];  // V rows for this thread's column, all K neighbors
  #pragma unroll
  for (int kt = 0; kt < K_; kt += KT) {
    // stage xk rows for KT neighbors
    #pragma unroll
    for (int u = 0; u < KT; u++) {
      int k = kt + u;
      int nb = nbs[k];
      size_t nbg = (size_t)(b * N_ + nb) * H_;
      float c0 = hE[(size_t)(node * K_ + k) * H_ + t];
      if (ENC) {
        xk[u * XCH + t] = c0;
        xk[u * XCH + H_ + t] = hV_in[nbg + t];
      } else {
        float ar = (nb < n) ? 1.f : 0.f;
        float bw = mi * ar, fw = mi * (1.f - ar);
        xk[u * XCH + t] = mi * c0;
        xk[u * XCH + H_ + t] = bw * hS[nbg + t];
        xk[u * XCH + 2 * H_ + t] = bw * hV_in[nbg + t] + fw * hVenc[nbg + t];
      }
    }
    __syncthreads();

    float kv[KT], vv[KT];
    #pragma unroll
    for (int u = 0; u < KT; u++) { kv[u] = 0.f; vv[u] = 0.f; }
    for (int j4 = 0; j4 < XCH / 4; j4++) {
      int j = j4 * 4;
      float wk0 = WK[(j + 0) * H_ + t], wk1 = WK[(j + 1) * H_ + t];
      float wk2 = WK[(j + 2) * H_ + t], wk3 = WK[(j + 3) * H_ + t];
      float wv0 = WV[(j + 0) * H_ + t], wv1 = WV[(j + 1) * H_ + t];
      float wv2 = WV[(j + 2) * H_ + t], wv3 = WV[(j + 3) * H_ + t];
      #pragma unroll
      for (int u = 0; u < KT; u++) {
        float4 xv = *((const float4*)(xk + u * XCH + j));
        kv[u] = fmaf(xv.x, wk0, fmaf(xv.y, wk1, fmaf(xv.z, wk2, fmaf(xv.w, wk3, kv[u]))));
        vv[u] = fmaf(xv.x, wv0, fmaf(xv.y, wv1, fmaf(xv.z, wv2, fmaf(xv.w, wv3, vv[u]))));
      }
    }
    #pragma unroll
    for (int u = 0; u < KT; u++) {
      int k = kt + u;
      vvAll[k] = vv[u];
      float prod = qreg * kv[u];
      #pragma unroll
      for (int off = 16; off > 0; off >>= 1) prod += __shfl_xor(prod, off, 32);
      if (lane32 == 0) {
        float lg = prod * 0.17677669529663687f;  // 1/sqrt(32)
        if (ENC) {
          float m2 = mi * mask[b * N_ + nbs[k]];
          sc[head * K_ + k] = (m2 > 0.f) ? lg : NEG_INF_;
        } else {
          sc[head * K_ + k] = lg;
        }
      }
    }
    __syncthreads();  // xk reuse + sc visibility
  }

  if (t < NH_) {
    float mx = -3.4e38f;
    for (int k = 0; k < K_; k++) mx = fmaxf(mx, sc[t * K_ + k]);
    float s = 0.f;
    for (int k = 0; k < K_; k++) { float ev = expf(sc[t * K_ + k] - mx); att[t * K_ + k] = ev; s += ev; }
    float inv = 1.f / s;
    for (int k = 0; k < K_; k++) att[t * K_ + k] *= inv;
  }
  __syncthreads();
  if (ENC && t < K_) {
    float m2 = mi * mask[b * N_ + nbs[t]];
    for (int hh = 0; hh < NH_; hh++) att[hh * K_ + t] *= m2;
  }
  __syncthreads();
  float o = 0.f;
  #pragma unroll
  for (int k = 0; k < K_; k++) o = fmaf(att[head * K_ + k], vvAll[k], o);
  ob[t] = o; __syncthreads();
  float dh = 0.f;
  for (int j4 = 0; j4 < H_ / 4; j4++) {
    float4 ov = ((const float4*)ob)[j4];
    int j = j4 * 4;
    dh = fmaf(ov.x, WO[(j + 0) * H_ + t],
         fmaf(ov.y, WO[(j + 1) * H_ + t],
         fmaf(ov.z, WO[(j + 2) * H_ + t],
         fmaf(ov.w, WO[(j + 3) * H_ + t], dh))));
  }
  float r = x0[t] + dh;
  float mean = block_sum128f(r, red) * (1.f / H_);
  float d0 = r - mean;
  float var = block_sum128f(d0 * d0, red) * (1.f / H_);
  hV_out[(size_t)node * H_ + t] = d0 * rsqrtf(var + 1e-6f);
}

// ---------------- FFN + residual LN + node mask (in-place, fp32 vectorized) ----------------
__global__ __launch_bounds__(H_) void ffn_kernel(float* __restrict__ hV, const float* __restrict__ mask,
    const float* __restrict__ W1, const float* __restrict__ b1,
    const float* __restrict__ W2, const float* __restrict__ b2) {
  int node = blockIdx.x, t = threadIdx.x;
  __shared__ __attribute__((aligned(16))) float x[H_];
  __shared__ __attribute__((aligned(16))) float hid[4 * H_];
  __shared__ float red[H_];
  x[t] = hV[(size_t)node * H_ + t];
  __syncthreads();
  #pragma unroll
  for (int c = 0; c < 4; c++) {
    float a = b1[c * H_ + t];
    for (int h4 = 0; h4 < H_ / 4; h4++) {
      float4 xv = ((const float4*)x)[h4];
      int h = h4 * 4;
      a = fmaf(xv.x, W1[(h + 0) * 4 * H_ + c * H_ + t],
          fmaf(xv.y, W1[(h + 1) * 4 * H_ + c * H_ + t],
          fmaf(xv.z, W1[(h + 2) * 4 * H_ + c * H_ + t],
          fmaf(xv.w, W1[(h + 3) * 4 * H_ + c * H_ + t], a))));
    }
    hid[c * H_ + t] = fmaxf(a, 0.f);
  }
  __syncthreads();
  float o = b2[t];
  for (int j4 = 0; j4 < (4 * H_) / 4; j4++) {
    float4 hv = ((const float4*)hid)[j4];
    int j = j4 * 4;
    o = fmaf(hv.x, W2[(j + 0) * H_ + t],
        fmaf(hv.y, W2[(j + 1) * H_ + t],
        fmaf(hv.z, W2[(j + 2) * H_ + t],
        fmaf(hv.w, W2[(j + 3) * H_ + t], o))));
  }
  float r = x[t] + o;
  float mean = block_sum128f(r, red) * (1.f / H_);
  float d0 = r - mean;
  float var = block_sum128f(d0 * d0, red) * (1.f / H_);
  float y = d0 * rsqrtf(var + 1e-6f);
  y *= mask[node];
  hV[(size_t)node * H_ + t] = y;
}

// ---------------- output: log_softmax(hV @ W_out + b_out), fp32 out ----------------
__global__ __launch_bounds__(64) void out_kernel(const float* __restrict__ hV,
    const float* __restrict__ Wout, const float* __restrict__ bout, float* __restrict__ out) {
  int node = blockIdx.x, t = threadIdx.x;
  __shared__ float x[H_];
  __shared__ double lg[V_];
  __shared__ double lse;
  x[t] = hV[(size_t)node * H_ + t];
  x[t + 64] = hV[(size_t)node * H_ + t + 64];
  __syncthreads();
  if (t < V_) {
    double a = (double)bout[t];
    for (int h = 0; h < H_; h++) a += (double)x[h] * (double)Wout[h * V_ + t];
    lg[t] = a;
  }
  __syncthreads();
  if (t == 0) {
    double mx = -1e300;
    for (int v = 0; v < V_; v++) mx = fmax(mx, lg[v]);
    double s = 0.0;
    for (int v = 0; v < V_; v++) s += exp(lg[v] - mx);
    lse = mx + log(s);
  }
  __syncthreads();
  if (t < V_) out[(size_t)node * V_ + t] = (float)(lg[t] - lse);
}

// ---------------- host ----------------
extern "C" void kernel_launch(void* const* d_in, const int* in_sizes, int n_in,
                              void* d_out, int out_size, void* d_ws, size_t ws_size,
                              hipStream_t stream) {
  const float* X    = (const float*)d_in[0];
  const float* mask = (const float*)d_in[1];
  const int*   S    = (const int*)d_in[2];
  const float* Wfn  = (const float*)d_in[3];
  const float* bfn  = (const float*)d_in[4];
  const float* Wfe  = (const float*)d_in[5];
  const float* bfe  = (const float*)d_in[6];
  const float* Wv   = (const float*)d_in[7];
  const float* bv   = (const float*)d_in[8];
  const float* We   = (const float*)d_in[9];
  const float* be   = (const float*)d_in[10];
  const float* Ws   = (const float*)d_in[11];
  const float* eWQ  = (const float*)d_in[12];
  const float* eWK  = (const float*)d_in[13];
  const float* eWV  = (const float*)d_in[14];
  const float* eWO  = (const float*)d_in[15];
  const float* eW1  = (const float*)d_in[16];
  const float* eb1  = (const float*)d_in[17];
  const float* eW2  = (const float*)d_in[18];
  const float* eb2  = (const float*)d_in[19];
  const float* dWQ  = (const float*)d_in[20];
  const float* dWK  = (const float*)d_in[21];
  const float* dWV  = (const float*)d_in[22];
  const float* dWO  = (const float*)d_in[23];
  const float* dW1  = (const float*)d_in[24];
  const float* db1  = (const float*)d_in[25];
  const float* dW2  = (const float*)d_in[26];
  const float* db2  = (const float*)d_in[27];
  const float* Wout = (const float*)d_in[28];
  const float* bout = (const float*)d_in[29];
  float* out = (float*)d_out;

  char* w = (char*)d_ws;
  int*    eidx = (int*)w;     w += (size_t)BN_ * K_ * 4;
  float*  dnb  = (float*)w;   w += (size_t)BN_ * K_ * 4;
  float*  vf   = (float*)w;   w += (size_t)BN_ * 6 * 4;
  float*  hS   = (float*)w;   w += (size_t)BN_ * H_ * 4;
  float*  hVa  = (float*)w;   w += (size_t)BN_ * H_ * 4;
  float*  hVb  = (float*)w;   w += (size_t)BN_ * H_ * 4;
  float*  hVc  = (float*)w;   w += (size_t)BN_ * H_ * 4;
  float*  hE   = (float*)w;   w += (size_t)BN_ * K_ * H_ * 4;

  topk_kernel<<<BN_, 256, 0, stream>>>(X, mask, eidx, dnb);
  dihedral_kernel<<<(BN_ + 255) / 256, 256, 0, stream>>>(X, vf);
  node_embed_kernel<<<BN_, H_, 0, stream>>>(vf, Wfn, bfn, Wv, bv, hVa);
  edge_embed_kernel<<<BN_ * K_, H_, 0, stream>>>(eidx, dnb, Wfe, bfe, We, be, hE);
  hs_kernel<<<(BN_ * H_ + 255) / 256, 256, 0, stream>>>(S, Ws, hS);

  // encoder: a->b, b->a, a->b
  float* cur = hVa; float* nxt = hVb;
  for (int l = 0; l < 3; l++) {
    attn_kernel<2, true><<<BN_, H_, 0, stream>>>(cur, hE, nullptr, nullptr, eidx, mask,
        eWQ + (size_t)l * H_ * H_, eWK + (size_t)l * 2 * H_ * H_,
        eWV + (size_t)l * 2 * H_ * H_, eWO + (size_t)l * H_ * H_, nxt);
    ffn_kernel<<<BN_, H_, 0, stream>>>(nxt, mask,
        eW1 + (size_t)l * H_ * 4 * H_, eb1 + (size_t)l * 4 * H_,
        eW2 + (size_t)l * 4 * H_ * H_, eb2 + (size_t)l * H_);
    float* tmp = cur; cur = nxt; nxt = tmp;
  }
  float* henc = cur;  // = hVb
  // decoder: henc->a, a->c, c->a (henc preserved)
  float* din = henc;
  float* douts[3] = { hVa, hVc, hVa };
  for (int l = 0; l < 3; l++) {
    attn_kernel<3, false><<<BN_, H_, 0, stream>>>(din, hE, hS, henc, eidx, mask,
        dWQ + (size_t)l * H_ * H_, dWK + (size_t)l * 3 * H_ * H_,
        dWV + (size_t)l * 3 * H_ * H_, dWO + (size_t)l * H_ * H_, douts[l]);
    ffn_kernel<<<BN_, H_, 0, stream>>>(douts[l], mask,
        dW1 + (size_t)l * H_ * 4 * H_, db1 + (size_t)l * 4 * H_,
        dW2 + (size_t)l * 4 * H_ * H_, db2 + (size_t)l * H_);
    din = douts[l];
  }
  out_kernel<<<BN_, 64, 0, stream>>>(din, Wout, bout, out);
}